// Round 1
// baseline (1410.161 us; speedup 1.0000x reference)
//
#include <hip/hip_runtime.h>
#include <hip/hip_bf16.h>
#include <stdint.h>

// Problem constants
#define B_    16
#define C_IN  64
#define C_OUT 32
#define V_HI  163842
#define V_LO  40962
#define K_    7

#define OUT_ELEMS ((size_t)B_ * C_OUT * V_HI)   // 83,887,104 u32 = 335.5 MB
#define OUT_U4    (OUT_ELEMS / 4)               // 20,971,776 (exact)

// ---------------------------------------------------------------------------
// Zero-fill the packed output buffer (streaming dwordx4 stores, ~full BW).
// ---------------------------------------------------------------------------
__global__ __launch_bounds__(256) void zero_k(uint4* __restrict__ p)
{
    size_t i = (size_t)blockIdx.x * 256 + threadIdx.x;
    const size_t stride = (size_t)gridDim.x * 256;
    const uint4 z = make_uint4(0u, 0u, 0u, 0u);
    for (; i < OUT_U4; i += stride) p[i] = z;
}

// ---------------------------------------------------------------------------
// Fused: h[b,o,v] = sum_c x[b,c,v]*W[o,c] + bias[o]  (bf16-rounded), then
// forward scatter-max:  u = up[down[v]*K + mp[b,o,v]]
//   atomicMax(out[b,o,u], (v<<16) | bf16bits(h))
// "max v wins" == reference's last-index-wins scatter (v ascending per o).
// Atomics are no-return (fire-and-forget), uniformly scattered: ~8 per
// 128B line of out, so this pass is line-fill BW-bound, not contention-bound.
// ---------------------------------------------------------------------------
__global__ __launch_bounds__(256) void fused_scatter_k(
    const float* __restrict__ x, const float* __restrict__ W,
    const float* __restrict__ bias, const int* __restrict__ mp,
    const int* __restrict__ up, const int* __restrict__ down,
    unsigned* __restrict__ out)
{
    __shared__ float sW[C_OUT * C_IN];   // 8 KB
    __shared__ float sB[C_OUT];
    __shared__ int   sRow[K_ * 256];     // 7 KB; sRow[k*256+t]: bank = t%32,
                                         // conflict-free for any per-lane k
    int t = threadIdx.x;
    for (int i = t; i < C_OUT * C_IN; i += 256) sW[i] = W[i];
    if (t < C_OUT) sB[t] = bias[t];

    int b = blockIdx.y;
    int v = blockIdx.x * 256 + t;
    bool valid = (v < V_LO);
    int d = valid ? down[v] : 0;
#pragma unroll
    for (int k = 0; k < K_; ++k)
        sRow[k * 256 + t] = valid ? up[(size_t)d * K_ + k] : 0;
    __syncthreads();
    if (!valid) return;

    const float* xp = x + (size_t)b * C_IN * V_LO + v;
    float acc[C_OUT];
#pragma unroll
    for (int o = 0; o < C_OUT; ++o) acc[o] = 0.0f;

    for (int c = 0; c < C_IN; ++c) {
        float xv = xp[(size_t)c * V_LO];          // coalesced across lanes
#pragma unroll
        for (int o = 0; o < C_OUT; ++o)
            acc[o] += xv * sW[o * C_IN + c];      // LDS broadcast (free)
    }

    const int* mpp = mp + (size_t)b * C_OUT * V_LO + v;
    const unsigned vhi = (unsigned)v << 16;       // v < 40962 fits 16 bits
#pragma unroll
    for (int o = 0; o < C_OUT; ++o) {
        int k = mpp[(size_t)o * V_LO] & 7;        // coalesced read of mp
        int u = sRow[k * 256 + t];
        __hip_bfloat16 hv = __float2bfloat16(acc[o] + sB[o]);  // same rounding as prev kernel
        unsigned hb = (unsigned)(*reinterpret_cast<unsigned short*>(&hv));
        atomicMax(&out[((size_t)(b * C_OUT + o)) * V_HI + u], vhi | hb);
    }
}

// ---------------------------------------------------------------------------
// Finalize in place: winner packed (v<<16)|hbits -> float bits hbits<<16.
// Untouched (zero) elements stay 0.0f. Vectorized uint4 RMW at HBM BW.
// ---------------------------------------------------------------------------
__global__ __launch_bounds__(256) void finalize_k(uint4* __restrict__ p)
{
    size_t i = (size_t)blockIdx.x * 256 + threadIdx.x;
    const size_t stride = (size_t)gridDim.x * 256;
    for (; i < OUT_U4; i += stride) {
        uint4 q = p[i];
        q.x = (q.x & 0xFFFFu) << 16;
        q.y = (q.y & 0xFFFFu) << 16;
        q.z = (q.z & 0xFFFFu) << 16;
        q.w = (q.w & 0xFFFFu) << 16;
        p[i] = q;
    }
}

// ---------------------------------------------------------------------------
extern "C" void kernel_launch(void* const* d_in, const int* in_sizes, int n_in,
                              void* d_out, int out_size, void* d_ws, size_t ws_size,
                              hipStream_t stream)
{
    const float* x    = (const float*)d_in[0];
    const float* W    = (const float*)d_in[1];
    const float* bias = (const float*)d_in[2];
    const int*   mp   = (const int*)d_in[3];
    const int*   up   = (const int*)d_in[4];
    const int*   down = (const int*)d_in[5];
    unsigned* outp = (unsigned*)d_out;

    (void)d_ws; (void)ws_size; (void)in_sizes; (void)n_in; (void)out_size;

    // 1) zero packed output (candidates are all >= 0; zero = "no write")
    zero_k<<<8192, 256, 0, stream>>>((uint4*)outp);

    // 2) fused h-compute + forward scatter-max
    {
        dim3 grid((V_LO + 255) / 256, B_);
        fused_scatter_k<<<grid, 256, 0, stream>>>(x, W, bias, mp, up, down, outp);
    }

    // 3) packed -> float, in place
    finalize_k<<<8192, 256, 0, stream>>>((uint4*)outp);
}

// Round 2
// 979.566 us; speedup vs baseline: 1.4396x; 1.4396x over previous
//
#include <hip/hip_runtime.h>
#include <hip/hip_bf16.h>
#include <stdint.h>

// Problem constants
#define B_    16
#define C_IN  64
#define C_OUT 32
#define V_HI  163842
#define V_LO  40962
#define K_    7
#define NPLANE (B_ * C_OUT)        // 512

// LDS chunking of the u-range: 5 chunks of 32772 u32 slots = 131088 B LDS
#define CH      32772
#define NCHUNK  5                  // 5*32772 = 163860 >= V_HI
#define CH_BYTES (CH * 4)          // 131088 < 160 KiB

// ---------------------------------------------------------------------------
// prow[v][k] = up[down[v]][k]  -- compacts the double indirection into a
// 1.15 MB table with v-contiguous rows (L2-resident, gather-friendly).
// ---------------------------------------------------------------------------
__global__ __launch_bounds__(256) void prow_k(
    const int* __restrict__ up, const int* __restrict__ down,
    int* __restrict__ prow)
{
    int v = blockIdx.x * 256 + threadIdx.x;
    if (v >= V_LO) return;
    int d = down[v];
    const int* r = up + (size_t)d * K_;
    int* w = prow + (size_t)v * K_;
#pragma unroll
    for (int k = 0; k < K_; ++k) w[k] = r[k];
}

// ---------------------------------------------------------------------------
// h[plane][v] = bf16( sum_c x[b,c,v]*W[o,c] + bias[o] ), plane = b*C_OUT+o
// ---------------------------------------------------------------------------
__global__ __launch_bounds__(256) void compute_h_k(
    const float* __restrict__ x, const float* __restrict__ W,
    const float* __restrict__ bias, __hip_bfloat16* __restrict__ h)
{
    __shared__ float sW[C_OUT * C_IN];   // 8 KB
    __shared__ float sB[C_OUT];
    int t = threadIdx.x;
    for (int i = t; i < C_OUT * C_IN; i += 256) sW[i] = W[i];
    if (t < C_OUT) sB[t] = bias[t];
    __syncthreads();

    int b = blockIdx.y;
    int v = blockIdx.x * 256 + t;
    if (v >= V_LO) return;

    const float* xp = x + (size_t)b * C_IN * V_LO + v;
    float acc[C_OUT];
#pragma unroll
    for (int o = 0; o < C_OUT; ++o) acc[o] = 0.0f;

    for (int c = 0; c < C_IN; ++c) {
        float xv = xp[(size_t)c * V_LO];          // coalesced across lanes
#pragma unroll
        for (int o = 0; o < C_OUT; ++o)
            acc[o] += xv * sW[o * C_IN + c];      // LDS broadcast (free)
    }

    __hip_bfloat16* hp = h + (size_t)b * C_OUT * V_LO + v;
#pragma unroll
    for (int o = 0; o < C_OUT; ++o)
        hp[(size_t)o * V_LO] = __float2bfloat16(acc[o] + sB[o]);
}

// ---------------------------------------------------------------------------
// One block per (plane, chunk). Winner resolution entirely in LDS:
//   packed = (v<<16) | bf16bits(h);  max over packed == max v (v distinct
//   per plane, v<40962 fits 16 bits) == reference last-index-wins.
// packed==0 only when no candidate OR winner h==+0.0; both emit 0.0f,
// identical to the reference either way. Finalize fused into the write-out.
// ---------------------------------------------------------------------------
__global__ __launch_bounds__(1024) void scatter_k(
    const int* __restrict__ mp, const int* __restrict__ prow,
    const ushort* __restrict__ h, float* __restrict__ out)
{
    extern __shared__ unsigned s[];              // CH slots
    int t     = threadIdx.x;
    int chunk = blockIdx.x;                      // 0..4
    int plane = blockIdx.y;                      // 0..511
    int base  = chunk * CH;
    int lim   = min(CH, V_HI - base);

    // zero LDS (vectorized: 32772/4 = 8193 uint4)
    uint4* s4 = (uint4*)s;
    const uint4 z = make_uint4(0u, 0u, 0u, 0u);
    for (int i = t; i < 8193; i += 1024) s4[i] = z;
    __syncthreads();

    const int*    mpp = mp + (size_t)plane * V_LO;
    const ushort* hp  = h  + (size_t)plane * V_LO;

    // scan all v; lanes hold consecutive v so the prow gather per wave-inst
    // spans a small contiguous region (good L1/L2 line sharing)
#pragma unroll 8
    for (int i = 0; i < 40; ++i) {               // 40*1024 = 40960
        int v = t + i * 1024;
        int k = mpp[v] & 7;                      // coalesced
        unsigned hv = hp[v];                     // coalesced (issued early)
        unsigned u  = (unsigned)prow[v * K_ + k];// small L2-resident gather
        unsigned d  = u - (unsigned)base;
        if (d < (unsigned)CH)
            atomicMax(&s[d], ((unsigned)v << 16) | hv);   // on-CU resolve
    }
    if (t < 2) {                                 // tail v = 40960, 40961
        int v = 40960 + t;
        int k = mpp[v] & 7;
        unsigned hv = hp[v];
        unsigned u  = (unsigned)prow[v * K_ + k];
        unsigned d  = u - (unsigned)base;
        if (d < (unsigned)CH)
            atomicMax(&s[d], ((unsigned)v << 16) | hv);
    }
    __syncthreads();

    // coalesced write-out with fused bf16->f32 (zeros stay 0.0f)
    float* op = out + (size_t)plane * V_HI + base;
    for (int i = t; i < lim; i += 1024)
        op[i] = __uint_as_float((s[i] & 0xFFFFu) << 16);
}

// ---------------------------------------------------------------------------
extern "C" void kernel_launch(void* const* d_in, const int* in_sizes, int n_in,
                              void* d_out, int out_size, void* d_ws, size_t ws_size,
                              hipStream_t stream)
{
    const float* x    = (const float*)d_in[0];
    const float* W    = (const float*)d_in[1];
    const float* bias = (const float*)d_in[2];
    const int*   mp   = (const int*)d_in[3];
    const int*   up   = (const int*)d_in[4];
    const int*   down = (const int*)d_in[5];
    float* outp = (float*)d_out;

    (void)in_sizes; (void)n_in; (void)out_size; (void)ws_size;

    // Workspace: h (bf16) then prow
    char* ws = (char*)d_ws;
    const size_t H_BYTES = (size_t)NPLANE * V_LO * 2;   // 41,945,088
    ushort* h    = (ushort*)ws;
    int*    prow = (int*)(ws + H_BYTES);                // +1,146,936  (~43 MB total)

    // opt in to >64KB dynamic LDS (idempotent, no stream work -> capture safe)
    (void)hipFuncSetAttribute((const void*)scatter_k,
                              hipFuncAttributeMaxDynamicSharedMemorySize,
                              CH_BYTES);

    // 1) compact indirection table
    prow_k<<<(V_LO + 255) / 256, 256, 0, stream>>>(up, down, prow);

    // 2) h = x W + b  (bf16)
    {
        dim3 grid((V_LO + 255) / 256, B_);
        compute_h_k<<<grid, 256, 0, stream>>>(x, W, bias, (__hip_bfloat16*)h);
    }

    // 3) LDS-chunked scatter-max + fused finalize
    {
        dim3 grid(NCHUNK, NPLANE);
        scatter_k<<<grid, 1024, CH_BYTES, stream>>>(mp, prow, h, outp);
    }
}